// Round 1
// baseline (6962.705 us; speedup 1.0000x reference)
//
#include <hip/hip_runtime.h>

// ---------------------------------------------------------------------------
// HeteroTripartiteGCN: dense 64x64 transforms + 6 COO scatter-SpMMs + ReLU.
// Layout of d_out: [msg_u (NU*64) | msg_v (NV*64) | msg_f (NF*64)], fp32.
// d_ws holds the 6 transformed feature matrices (~79.4 MB).
// ---------------------------------------------------------------------------

#define TDIM 64

// Y1 = X @ W1, Y2 = X @ W2  for X (N x 64), W (64 x 64).
// Block: 256 threads, 64 rows per block. Register-blocked 4x4 per thread.
__global__ __launch_bounds__(256) void transform2_kernel(
    const float* __restrict__ X, const float* __restrict__ W1,
    const float* __restrict__ W2, float* __restrict__ Y1,
    float* __restrict__ Y2, int N)
{
    __shared__ float xsT[64 * 68];   // [k][r], stride 68 (16B-aligned rows, breaks pow2)
    __shared__ float w1s[64 * 64];   // [k][c]
    __shared__ float w2s[64 * 64];

    const int tid  = threadIdx.x;
    const int row0 = blockIdx.x * 64;

    // Load both weight matrices (4096 floats each) into LDS, float4-vectorized.
    for (int i = tid * 4; i < 4096; i += 256 * 4) {
        *(float4*)&w1s[i] = *(const float4*)&W1[i];
        *(float4*)&w2s[i] = *(const float4*)&W2[i];
    }

    // Load 64x64 X tile, store transposed: xsT[k][r] = X[row0+r][k].
    {
        const int r  = tid >> 2;          // 0..63
        const int c0 = (tid & 3) * 16;    // 0,16,32,48
        const int gr = row0 + r;
        #pragma unroll
        for (int cc = 0; cc < 16; cc += 4) {
            const int c = c0 + cc;
            float4 v = make_float4(0.f, 0.f, 0.f, 0.f);
            if (gr < N) v = *(const float4*)&X[(size_t)gr * TDIM + c];
            xsT[(c + 0) * 68 + r] = v.x;
            xsT[(c + 1) * 68 + r] = v.y;
            xsT[(c + 2) * 68 + r] = v.z;
            xsT[(c + 3) * 68 + r] = v.w;
        }
    }
    __syncthreads();

    const int tx = tid & 15;   // col group: cols [tx*4, tx*4+4)
    const int ty = tid >> 4;   // row group: rows [ty*4, ty*4+4)

    float a1[4][4] = {{0.f}}, a2[4][4] = {{0.f}};

    #pragma unroll 8
    for (int k = 0; k < 64; ++k) {
        const float4 xv = *(const float4*)&xsT[k * 68 + ty * 4];
        const float4 w1 = *(const float4*)&w1s[k * 64 + tx * 4];
        const float4 w2 = *(const float4*)&w2s[k * 64 + tx * 4];
        const float xr[4]  = {xv.x, xv.y, xv.z, xv.w};
        const float c1[4]  = {w1.x, w1.y, w1.z, w1.w};
        const float c2[4]  = {w2.x, w2.y, w2.z, w2.w};
        #pragma unroll
        for (int r = 0; r < 4; ++r)
            #pragma unroll
            for (int c = 0; c < 4; ++c) {
                a1[r][c] = fmaf(xr[r], c1[c], a1[r][c]);
                a2[r][c] = fmaf(xr[r], c2[c], a2[r][c]);
            }
    }

    #pragma unroll
    for (int r = 0; r < 4; ++r) {
        const int gr = row0 + ty * 4 + r;
        if (gr < N) {
            float4 o1 = make_float4(a1[r][0], a1[r][1], a1[r][2], a1[r][3]);
            float4 o2 = make_float4(a2[r][0], a2[r][1], a2[r][2], a2[r][3]);
            *(float4*)&Y1[(size_t)gr * TDIM + tx * 4] = o1;
            *(float4*)&Y2[(size_t)gr * TDIM + tx * 4] = o2;
        }
    }
}

// COO scatter: dst[rows[e]] += vals[e] * src[cols[e]], 16 lanes per edge,
// float4 gather + 4 scalar fp32 atomics per lane.
__global__ __launch_bounds__(256) void scatter_kernel(
    const int* __restrict__ rows, const int* __restrict__ cols,
    const float* __restrict__ vals, const float* __restrict__ src,
    float* __restrict__ dst, int n_edges)
{
    const int gid = blockIdx.x * 256 + threadIdx.x;
    const int e   = gid >> 4;
    const int l   = gid & 15;
    if (e >= n_edges) return;

    const int   r = rows[e];
    const int   c = cols[e];
    const float v = vals[e];

    const float4 s = *(const float4*)&src[(size_t)c * TDIM + l * 4];
    float* d = &dst[(size_t)r * TDIM + l * 4];
    atomicAdd(d + 0, v * s.x);
    atomicAdd(d + 1, v * s.y);
    atomicAdd(d + 2, v * s.z);
    atomicAdd(d + 3, v * s.w);
}

__global__ __launch_bounds__(256) void relu_kernel(float* __restrict__ p, int n4)
{
    const int i = blockIdx.x * 256 + threadIdx.x;
    if (i < n4) {
        float4 v = ((float4*)p)[i];
        v.x = fmaxf(v.x, 0.f);
        v.y = fmaxf(v.y, 0.f);
        v.z = fmaxf(v.z, 0.f);
        v.w = fmaxf(v.w, 0.f);
        ((float4*)p)[i] = v;
    }
}

extern "C" void kernel_launch(void* const* d_in, const int* in_sizes, int n_in,
                              void* d_out, int out_size, void* d_ws, size_t ws_size,
                              hipStream_t stream)
{
    // ---- inputs (setup_inputs dict order) ----
    const float* x_u    = (const float*)d_in[0];
    const float* x_v    = (const float*)d_in[1];
    const float* x_f    = (const float*)d_in[2];
    const float* W_u_uv = (const float*)d_in[3];
    const float* W_v_uv = (const float*)d_in[4];
    const float* W_f2u  = (const float*)d_in[5];
    const float* W_f2v  = (const float*)d_in[6];
    const float* W_u2f  = (const float*)d_in[7];
    const float* W_v2f  = (const float*)d_in[8];

    const int* uv_rows = (const int*)d_in[9];
    const int* uv_cols = (const int*)d_in[10];
    const float* uv_vals = (const float*)d_in[11];
    const int* vu_rows = (const int*)d_in[12];
    const int* vu_cols = (const int*)d_in[13];
    const float* vu_vals = (const float*)d_in[14];
    const int* uf_rows = (const int*)d_in[15];
    const int* uf_cols = (const int*)d_in[16];
    const float* uf_vals = (const float*)d_in[17];
    const int* vf_rows = (const int*)d_in[18];
    const int* vf_cols = (const int*)d_in[19];
    const float* vf_vals = (const float*)d_in[20];
    const int* fu_rows = (const int*)d_in[21];
    const int* fu_cols = (const int*)d_in[22];
    const float* fu_vals = (const float*)d_in[23];
    const int* fv_rows = (const int*)d_in[24];
    const int* fv_cols = (const int*)d_in[25];
    const float* fv_vals = (const float*)d_in[26];

    const int NU = in_sizes[0] / TDIM;
    const int NV = in_sizes[1] / TDIM;
    const int NF = in_sizes[2] / TDIM;
    const int E_uv = in_sizes[9];
    const int E_vu = in_sizes[12];
    const int E_uf = in_sizes[15];
    const int E_vf = in_sizes[18];
    const int E_fu = in_sizes[21];
    const int E_fv = in_sizes[24];

    // ---- workspace layout: 6 transformed feature matrices ----
    float* ws    = (float*)d_ws;
    float* tmp_u = ws;                                  // NU*64  (x_u @ W_u_uv)
    float* u2f   = tmp_u + (size_t)NU * TDIM;           // NU*64  (x_u @ W_u2f)
    float* tmp_v = u2f   + (size_t)NU * TDIM;           // NV*64  (x_v @ W_v_uv)
    float* v2f   = tmp_v + (size_t)NV * TDIM;           // NV*64  (x_v @ W_v2f)
    float* f2u   = v2f   + (size_t)NV * TDIM;           // NF*64  (x_f @ W_f2u)
    float* f2v   = f2u   + (size_t)NF * TDIM;           // NF*64  (x_f @ W_f2v)

    float* msg_u = (float*)d_out;
    float* msg_v = msg_u + (size_t)NU * TDIM;
    float* msg_f = msg_v + (size_t)NV * TDIM;

    // d_out is poisoned before every timed replay — zero it ourselves.
    hipMemsetAsync(d_out, 0, (size_t)out_size * sizeof(float), stream);

    // ---- dense transforms (x read once, two weights applied) ----
    transform2_kernel<<<(NU + 63) / 64, 256, 0, stream>>>(x_u, W_u_uv, W_u2f, tmp_u, u2f, NU);
    transform2_kernel<<<(NV + 63) / 64, 256, 0, stream>>>(x_v, W_v_uv, W_v2f, tmp_v, v2f, NV);
    transform2_kernel<<<(NF + 63) / 64, 256, 0, stream>>>(x_f, W_f2u, W_f2v, f2u, f2v, NF);

    // ---- 6 COO scatter-SpMMs into d_out ----
    auto scat = [&](const int* r, const int* c, const float* v,
                    const float* s, float* d, int n) {
        const long long threads = (long long)n * 16;
        const int blocks = (int)((threads + 255) / 256);
        scatter_kernel<<<blocks, 256, 0, stream>>>(r, c, v, s, d, n);
    };
    scat(uv_rows, uv_cols, uv_vals, tmp_v, msg_u, E_uv);  // msg_u += uv @ tmp_v
    scat(vu_rows, vu_cols, vu_vals, tmp_u, msg_v, E_vu);  // msg_v += vu @ tmp_u
    scat(uf_rows, uf_cols, uf_vals, f2u,   msg_u, E_uf);  // msg_u += uf @ f2u
    scat(vf_rows, vf_cols, vf_vals, f2v,   msg_v, E_vf);  // msg_v += vf @ f2v
    scat(fu_rows, fu_cols, fu_vals, u2f,   msg_f, E_fu);  // msg_f += fu @ u2f
    scat(fv_rows, fv_cols, fv_vals, v2f,   msg_f, E_fv);  // msg_f += fv @ v2f

    // ---- ReLU in place ----
    const int n4 = out_size / 4;
    relu_kernel<<<(n4 + 255) / 256, 256, 0, stream>>>((float*)d_out, n4);
}

// Round 2
// 1399.510 us; speedup vs baseline: 4.9751x; 4.9751x over previous
//
#include <hip/hip_runtime.h>

// ---------------------------------------------------------------------------
// HeteroTripartiteGCN, round 2: atomics eliminated.
//   1) dense 64x64 transforms (x read once, two weights each)
//   2) device-side counting-sort of all 6 COO relations into one CSR arena
//      (histogram -> single global exclusive scan -> fill)
//   3) gather per destination row (wave per row, lane = feature), two
//      relations fused per output, ReLU fused into the write.
// d_out: [msg_u | msg_v | msg_f] fp32. No atomicAdd on fp32 anywhere.
// ---------------------------------------------------------------------------

#define TDIM   64
#define SCHUNK 2048   // elements per scan block (256 thr x 8)

// ---------------- dense transforms ----------------
__global__ __launch_bounds__(256) void transform2_kernel(
    const float* __restrict__ X, const float* __restrict__ W1,
    const float* __restrict__ W2, float* __restrict__ Y1,
    float* __restrict__ Y2, int N)
{
    __shared__ float xsT[64 * 68];
    __shared__ float w1s[64 * 64];
    __shared__ float w2s[64 * 64];

    const int tid  = threadIdx.x;
    const int row0 = blockIdx.x * 64;

    for (int i = tid * 4; i < 4096; i += 256 * 4) {
        *(float4*)&w1s[i] = *(const float4*)&W1[i];
        *(float4*)&w2s[i] = *(const float4*)&W2[i];
    }
    {
        const int r  = tid >> 2;
        const int c0 = (tid & 3) * 16;
        const int gr = row0 + r;
        #pragma unroll
        for (int cc = 0; cc < 16; cc += 4) {
            const int c = c0 + cc;
            float4 v = make_float4(0.f, 0.f, 0.f, 0.f);
            if (gr < N) v = *(const float4*)&X[(size_t)gr * TDIM + c];
            xsT[(c + 0) * 68 + r] = v.x;
            xsT[(c + 1) * 68 + r] = v.y;
            xsT[(c + 2) * 68 + r] = v.z;
            xsT[(c + 3) * 68 + r] = v.w;
        }
    }
    __syncthreads();

    const int tx = tid & 15;
    const int ty = tid >> 4;
    float a1[4][4] = {{0.f}}, a2[4][4] = {{0.f}};

    #pragma unroll 8
    for (int k = 0; k < 64; ++k) {
        const float4 xv = *(const float4*)&xsT[k * 68 + ty * 4];
        const float4 w1 = *(const float4*)&w1s[k * 64 + tx * 4];
        const float4 w2 = *(const float4*)&w2s[k * 64 + tx * 4];
        const float xr[4] = {xv.x, xv.y, xv.z, xv.w};
        const float c1[4] = {w1.x, w1.y, w1.z, w1.w};
        const float c2[4] = {w2.x, w2.y, w2.z, w2.w};
        #pragma unroll
        for (int r = 0; r < 4; ++r)
            #pragma unroll
            for (int c = 0; c < 4; ++c) {
                a1[r][c] = fmaf(xr[r], c1[c], a1[r][c]);
                a2[r][c] = fmaf(xr[r], c2[c], a2[r][c]);
            }
    }
    #pragma unroll
    for (int r = 0; r < 4; ++r) {
        const int gr = row0 + ty * 4 + r;
        if (gr < N) {
            *(float4*)&Y1[(size_t)gr * TDIM + tx * 4] =
                make_float4(a1[r][0], a1[r][1], a1[r][2], a1[r][3]);
            *(float4*)&Y2[(size_t)gr * TDIM + tx * 4] =
                make_float4(a2[r][0], a2[r][1], a2[r][2], a2[r][3]);
        }
    }
}

// ---------------- CSR build: histogram ----------------
__global__ __launch_bounds__(256) void hist_kernel(
    const int* __restrict__ rows, int* __restrict__ cnt, int base, int n)
{
    const int i = blockIdx.x * 256 + threadIdx.x;
    if (i < n) atomicAdd(&cnt[base + rows[i]], 1);
}

// ---------------- CSR build: 3-kernel exclusive scan ----------------
__global__ __launch_bounds__(256) void scan_partial_kernel(
    const int* __restrict__ cnt, int* __restrict__ partial, int n)
{
    __shared__ int sh[256];
    const int t    = threadIdx.x;
    const int base = blockIdx.x * SCHUNK + t * 8;
    int s = 0;
    #pragma unroll
    for (int i = 0; i < 8; ++i) {
        const int idx = base + i;
        if (idx < n) s += cnt[idx];
    }
    sh[t] = s;
    __syncthreads();
    for (int off = 128; off > 0; off >>= 1) {
        if (t < off) sh[t] += sh[t + off];
        __syncthreads();
    }
    if (t == 0) partial[blockIdx.x] = sh[0];
}

__global__ __launch_bounds__(256) void scan_root_kernel(
    int* __restrict__ partial, int nb, int* __restrict__ total_out)
{
    __shared__ int sh[256];
    const int t = threadIdx.x;
    sh[t] = (t < nb) ? partial[t] : 0;
    __syncthreads();
    for (int off = 1; off < 256; off <<= 1) {
        const int x = (t >= off) ? sh[t - off] : 0;
        __syncthreads();
        sh[t] += x;
        __syncthreads();
    }
    const int incl = sh[t];
    const int excl = (t == 0) ? 0 : sh[t - 1];
    if (t < nb) partial[t] = excl;
    if (t == nb - 1) *total_out = incl;
}

__global__ __launch_bounds__(256) void scan_chunks_kernel(
    const int* __restrict__ cnt, const int* __restrict__ partial,
    int* __restrict__ rowptr, int n)
{
    __shared__ int sh[256];
    const int t    = threadIdx.x;
    const int base = blockIdx.x * SCHUNK + t * 8;
    int v[8], ex[8], run = 0;
    #pragma unroll
    for (int i = 0; i < 8; ++i) {
        const int idx = base + i;
        v[i] = (idx < n) ? cnt[idx] : 0;
        ex[i] = run;
        run += v[i];
    }
    sh[t] = run;
    __syncthreads();
    for (int off = 1; off < 256; off <<= 1) {
        const int x = (t >= off) ? sh[t - off] : 0;
        __syncthreads();
        sh[t] += x;
        __syncthreads();
    }
    const int texcl = (t == 0) ? 0 : sh[t - 1];
    const int b     = partial[blockIdx.x] + texcl;
    #pragma unroll
    for (int i = 0; i < 8; ++i) {
        const int idx = base + i;
        if (idx < n) rowptr[idx] = b + ex[i];
    }
}

// ---------------- CSR build: fill arena ----------------
__global__ __launch_bounds__(256) void fill_kernel(
    const int* __restrict__ rows, const int* __restrict__ cols,
    const float* __restrict__ vals, int* __restrict__ cur, int base,
    int* __restrict__ acols, float* __restrict__ avals, int n)
{
    const int i = blockIdx.x * 256 + threadIdx.x;
    if (i < n) {
        const int r   = rows[i];
        const int pos = atomicAdd(&cur[base + r], 1);
        acols[pos] = cols[i];
        avals[pos] = vals[i];
    }
}

// ---------------- gather: wave per row, two relations fused, ReLU ----------
__global__ __launch_bounds__(256) void gather2_kernel(
    const int* __restrict__ rowptr, const int* __restrict__ acols,
    const float* __restrict__ avals,
    int baseA, const float* __restrict__ srcA,
    int baseB, const float* __restrict__ srcB,
    float* __restrict__ dst, int nrow)
{
    const int wid  = (blockIdx.x * 256 + threadIdx.x) >> 6;
    const int lane = threadIdx.x & 63;
    if (wid >= nrow) return;

    float acc = 0.f;

    {
        const int s = rowptr[baseA + wid];
        const int e = rowptr[baseA + wid + 1];
        int j = s;
        for (; j + 4 <= e; j += 4) {
            const int   c0 = acols[j], c1 = acols[j + 1], c2 = acols[j + 2], c3 = acols[j + 3];
            const float w0 = avals[j], w1 = avals[j + 1], w2 = avals[j + 2], w3 = avals[j + 3];
            const float x0 = srcA[(size_t)c0 * TDIM + lane];
            const float x1 = srcA[(size_t)c1 * TDIM + lane];
            const float x2 = srcA[(size_t)c2 * TDIM + lane];
            const float x3 = srcA[(size_t)c3 * TDIM + lane];
            acc = fmaf(w0, x0, acc);
            acc = fmaf(w1, x1, acc);
            acc = fmaf(w2, x2, acc);
            acc = fmaf(w3, x3, acc);
        }
        for (; j < e; ++j)
            acc = fmaf(avals[j], srcA[(size_t)acols[j] * TDIM + lane], acc);
    }
    {
        const int s = rowptr[baseB + wid];
        const int e = rowptr[baseB + wid + 1];
        int j = s;
        for (; j + 4 <= e; j += 4) {
            const int   c0 = acols[j], c1 = acols[j + 1], c2 = acols[j + 2], c3 = acols[j + 3];
            const float w0 = avals[j], w1 = avals[j + 1], w2 = avals[j + 2], w3 = avals[j + 3];
            const float x0 = srcB[(size_t)c0 * TDIM + lane];
            const float x1 = srcB[(size_t)c1 * TDIM + lane];
            const float x2 = srcB[(size_t)c2 * TDIM + lane];
            const float x3 = srcB[(size_t)c3 * TDIM + lane];
            acc = fmaf(w0, x0, acc);
            acc = fmaf(w1, x1, acc);
            acc = fmaf(w2, x2, acc);
            acc = fmaf(w3, x3, acc);
        }
        for (; j < e; ++j)
            acc = fmaf(avals[j], srcB[(size_t)acols[j] * TDIM + lane], acc);
    }

    dst[(size_t)wid * TDIM + lane] = fmaxf(acc, 0.f);
}

// ---------------------------------------------------------------------------
extern "C" void kernel_launch(void* const* d_in, const int* in_sizes, int n_in,
                              void* d_out, int out_size, void* d_ws, size_t ws_size,
                              hipStream_t stream)
{
    const float* x_u    = (const float*)d_in[0];
    const float* x_v    = (const float*)d_in[1];
    const float* x_f    = (const float*)d_in[2];
    const float* W_u_uv = (const float*)d_in[3];
    const float* W_v_uv = (const float*)d_in[4];
    const float* W_f2u  = (const float*)d_in[5];
    const float* W_f2v  = (const float*)d_in[6];
    const float* W_u2f  = (const float*)d_in[7];
    const float* W_v2f  = (const float*)d_in[8];

    const int* rows_[6] = {(const int*)d_in[9],  (const int*)d_in[12],
                           (const int*)d_in[15], (const int*)d_in[18],
                           (const int*)d_in[21], (const int*)d_in[24]};
    const int* cols_[6] = {(const int*)d_in[10], (const int*)d_in[13],
                           (const int*)d_in[16], (const int*)d_in[19],
                           (const int*)d_in[22], (const int*)d_in[25]};
    const float* vals_[6] = {(const float*)d_in[11], (const float*)d_in[14],
                             (const float*)d_in[17], (const float*)d_in[20],
                             (const float*)d_in[23], (const float*)d_in[26]};

    const int NU = in_sizes[0] / TDIM;
    const int NV = in_sizes[1] / TDIM;
    const int NF = in_sizes[2] / TDIM;
    const int E_[6] = {in_sizes[9], in_sizes[12], in_sizes[15],
                       in_sizes[18], in_sizes[21], in_sizes[24]};

    // relation row-count bases in the concatenated count array:
    // rel0 uv->NU, rel1 vu->NV, rel2 uf->NU, rel3 vf->NV, rel4 fu->NF, rel5 fv->NF
    const int nrow_[6] = {NU, NV, NU, NV, NF, NF};
    int base_[6];
    int ntot = 0;
    for (int r = 0; r < 6; ++r) { base_[r] = ntot; ntot += nrow_[r]; }
    size_t etot = 0;
    for (int r = 0; r < 6; ++r) etot += (size_t)E_[r];

    // ---- workspace layout (all 4-byte units) ----
    float* ws = (float*)d_ws;
    size_t o = 0;
    float* tmp_u = ws + o; o += (size_t)NU * TDIM;
    float* u2f   = ws + o; o += (size_t)NU * TDIM;
    float* tmp_v = ws + o; o += (size_t)NV * TDIM;
    float* v2f   = ws + o; o += (size_t)NV * TDIM;
    float* f2u   = ws + o; o += (size_t)NF * TDIM;
    float* f2v   = ws + o; o += (size_t)NF * TDIM;
    int* cnt     = (int*)(ws + o); o += ntot;
    int* rowptr  = (int*)(ws + o); o += ntot + 1;
    int* cur     = (int*)(ws + o); o += ntot;
    int* partial = (int*)(ws + o); o += 256;
    int*   acols = (int*)(ws + o); o += etot;
    float* avals = ws + o;         o += etot;
    (void)ws_size;

    float* msg_u = (float*)d_out;
    float* msg_v = msg_u + (size_t)NU * TDIM;
    float* msg_f = msg_v + (size_t)NV * TDIM;

    // ---- dense transforms ----
    transform2_kernel<<<(NU + 63) / 64, 256, 0, stream>>>(x_u, W_u_uv, W_u2f, tmp_u, u2f, NU);
    transform2_kernel<<<(NV + 63) / 64, 256, 0, stream>>>(x_v, W_v_uv, W_v2f, tmp_v, v2f, NV);
    transform2_kernel<<<(NF + 63) / 64, 256, 0, stream>>>(x_f, W_f2u, W_f2v, f2u, f2v, NF);

    // ---- CSR build ----
    hipMemsetAsync(cnt, 0, (size_t)ntot * sizeof(int), stream);
    for (int r = 0; r < 6; ++r)
        hist_kernel<<<(E_[r] + 255) / 256, 256, 0, stream>>>(rows_[r], cnt, base_[r], E_[r]);

    const int nb = (ntot + SCHUNK - 1) / SCHUNK;  // <= 256 for these sizes
    scan_partial_kernel<<<nb, 256, 0, stream>>>(cnt, partial, ntot);
    scan_root_kernel<<<1, 256, 0, stream>>>(partial, nb, &rowptr[ntot]);
    scan_chunks_kernel<<<nb, 256, 0, stream>>>(cnt, partial, rowptr, ntot);

    hipMemcpyAsync(cur, rowptr, (size_t)ntot * sizeof(int),
                   hipMemcpyDeviceToDevice, stream);
    for (int r = 0; r < 6; ++r)
        fill_kernel<<<(E_[r] + 255) / 256, 256, 0, stream>>>(
            rows_[r], cols_[r], vals_[r], cur, base_[r], acols, avals, E_[r]);

    // ---- fused gathers (+ReLU) ----
    gather2_kernel<<<(NU + 3) / 4, 256, 0, stream>>>(
        rowptr, acols, avals, base_[0], tmp_v, base_[2], f2u, msg_u, NU);
    gather2_kernel<<<(NV + 3) / 4, 256, 0, stream>>>(
        rowptr, acols, avals, base_[1], tmp_u, base_[3], f2v, msg_v, NV);
    gather2_kernel<<<(NF + 3) / 4, 256, 0, stream>>>(
        rowptr, acols, avals, base_[4], u2f, base_[5], v2f, msg_f, NF);
}